// Round 1
// baseline (1294.066 us; speedup 1.0000x reference)
//
#include <hip/hip_runtime.h>

#define DEV __device__ __forceinline__

// Knot j of the extended uniform grid: (j-3)*h + (-1), h = 0.4f  (fp32, matches jnp)
DEV float knot(int j) { return (float)(j - 3) * 0.4f - 1.0f; }

// f[0] = silu(x), f[1..8] = cubic B-spline bases (Cox-de Boor, grid_size=5, order=3)
DEV void kan_feats(float x, float f[9]) {
    float b[11];
#pragma unroll
    for (int j = 0; j < 11; ++j)
        b[j] = (x >= knot(j) && x < knot(j + 1)) ? 1.0f : 0.0f;
#pragma unroll
    for (int k = 1; k <= 3; ++k) {
#pragma unroll
        for (int j = 0; j < 11 - k; ++j) {
            // denominators are compile-time constants -> reciprocals fold
            const float left  = (x - knot(j)) * (1.0f / (knot(j + k) - knot(j)));
            const float right = (knot(j + k + 1) - x) * (1.0f / (knot(j + k + 1) - knot(j + 1)));
            b[j] = left * b[j] + right * b[j + 1];
        }
    }
    f[0] = x / (1.0f + __expf(-x));
#pragma unroll
    for (int t = 0; t < 8; ++t) f[t + 1] = b[t];
}

// Pack weights: dstT[(i*9 + t) * out_f + o], t=0 -> base weight, t=1+k -> sw*sc
__global__ __launch_bounds__(256) void pack_w9T(
    const float* __restrict__ bw, const float* __restrict__ sw,
    const float* __restrict__ sc, float* __restrict__ dstT,
    int out_f, int in_f) {
    const int idx = blockIdx.x * blockDim.x + threadIdx.x;
    if (idx >= out_f * in_f) return;
    const int o = idx / in_f, i = idx - o * in_f;
    const float s = sc[idx];
    dstT[(i * 9 + 0) * out_f + o] = bw[idx];
#pragma unroll
    for (int k = 0; k < 8; ++k)
        dstT[(i * 9 + 1 + k) * out_f + o] = sw[idx * 8 + k] * s;
}

// Fused unfold + KAN-linear + relu.  in: (B,CIN,H,W)  wT: (IN_F*9, OUT_F)  out: (B,OUT_F,Ho,Wo)
template <int CIN, int KS, int OUT_F, int STRIDE, int PAD, int TR, int SPLIT>
__global__ __launch_bounds__(256) void kan_conv(
    const float* __restrict__ in, const float* __restrict__ wT,
    float* __restrict__ out, int B, int H, int W, int Ho, int Wo) {
    constexpr int IN_F = CIN * KS * KS;
    constexpr int L = IN_F * 9;
    __shared__ float feat[TR][L];
    __shared__ float psum[256];
    const int tid = threadIdx.x;
    const int r0 = blockIdx.x * TR;
    const int HoWo = Ho * Wo;
    const int N = B * HoWo;

    // Phase 1: features for TR rows into LDS
    for (int idx = tid; idx < TR * IN_F; idx += 256) {
        const int r = idx / IN_F, i = idx - r * IN_F;
        const int n = r0 + r;
        float x = 0.0f;
        if (n < N) {
            const int wo = n % Wo, ho = (n / Wo) % Ho, bb = n / HoWo;
            const int ci = i / (KS * KS), rem = i - ci * (KS * KS);
            const int kh = rem / KS, kw = rem - kh * KS;
            const int hi = ho * STRIDE - PAD + kh, wi = wo * STRIDE - PAD + kw;
            if (hi >= 0 && hi < H && wi >= 0 && wi < W)
                x = in[((bb * CIN + ci) * H + hi) * W + wi];
        }
        float f9[9];
        kan_feats(x, f9);
#pragma unroll
        for (int t = 0; t < 9; ++t) feat[r][i * 9 + t] = f9[t];
    }
    __syncthreads();

    // Phase 2: dot(feat_row, wT[:,o])
    const int o = tid % OUT_F;
    float sum = 0.0f;
    int r;
    if constexpr (SPLIT == 2) {
        const int half = tid / 128;
        r = (tid & 127) / OUT_F;
        const int Lh = L / 2;
        const int j0 = half * Lh;
        const int j1 = half ? L : Lh;
        for (int j = j0; j < j1; ++j)
            sum += feat[r][j] * wT[j * OUT_F + o];
        psum[tid] = sum;
        __syncthreads();
        if (tid >= 128) return;
        sum += psum[tid + 128];
    } else {
        r = tid / OUT_F;
        for (int j = 0; j < L; ++j)
            sum += feat[r][j] * wT[j * OUT_F + o];
    }
    const int n = r0 + r;
    if (n < N) {
        const int wo = n % Wo, ho = (n / Wo) % Ho, bb = n / HoWo;
        out[((bb * OUT_F + o) * Ho + ho) * Wo + wo] = fmaxf(sum, 0.0f);
    }
}

// 2x2/2 max pool over (B*C, Hi, Wi) -> (B*C, Hi/2, Wi/2); input already relu'd
__global__ __launch_bounds__(256) void maxpool2x2(
    const float* __restrict__ in, float* __restrict__ out,
    int Hi, int Wi, int total) {
    const int idx = blockIdx.x * blockDim.x + threadIdx.x;
    if (idx >= total) return;
    const int Wo = Wi >> 1, Ho = Hi >> 1;
    const int wo = idx % Wo, ho = (idx / Wo) % Ho, bc = idx / (Wo * Ho);
    const float* p = in + ((size_t)bc * Hi + ho * 2) * Wi + wo * 2;
    out[idx] = fmaxf(fmaxf(p[0], p[1]), fmaxf(p[Wi], p[Wi + 1]));
}

__global__ __launch_bounds__(256) void mean_hw(
    const float* __restrict__ in, float* __restrict__ out, int HW, int total) {
    const int idx = blockIdx.x * blockDim.x + threadIdx.x;
    if (idx >= total) return;
    const float* p = in + (size_t)idx * HW;
    float s = 0.0f;
    for (int j = 0; j < HW; ++j) s += p[j];
    out[idx] = s / (float)HW;
}

// Classifier KAN-linear: in (8,64) -> out (8,200), no relu
__global__ __launch_bounds__(256) void kan_head(
    const float* __restrict__ in, const float* __restrict__ wT,
    float* __restrict__ out) {
    __shared__ float feat[64 * 9];
    const int n = blockIdx.x;
    const int tid = threadIdx.x;
    if (tid < 64) {
        float f9[9];
        kan_feats(in[n * 64 + tid], f9);
#pragma unroll
        for (int t = 0; t < 9; ++t) feat[tid * 9 + t] = f9[t];
    }
    __syncthreads();
    if (tid < 200) {
        float sum = 0.0f;
        for (int j = 0; j < 576; ++j)
            sum += feat[j] * wT[j * 200 + tid];
        out[n * 200 + tid] = sum;
    }
}

extern "C" void kernel_launch(void* const* d_in, const int* in_sizes, int n_in,
                              void* d_out, int out_size, void* d_ws, size_t ws_size,
                              hipStream_t stream) {
    const float* x   = (const float*)d_in[0];
    const float* bw0 = (const float*)d_in[1];
    const float* sw0 = (const float*)d_in[2];
    const float* sc0 = (const float*)d_in[3];
    const float* bw1 = (const float*)d_in[4];
    const float* sw1 = (const float*)d_in[5];
    const float* sc1 = (const float*)d_in[6];
    const float* bw2 = (const float*)d_in[7];
    const float* sw2 = (const float*)d_in[8];
    const float* sc2 = (const float*)d_in[9];
    const float* bwc = (const float*)d_in[10];
    const float* swc = (const float*)d_in[11];
    const float* scc = (const float*)d_in[12];
    float* out = (float*)d_out;

    char* ws = (char*)d_ws;
    size_t off = 0;
    auto alloc = [&](size_t nfloats) {
        float* p = (float*)(ws + off);
        off += ((nfloats * 4 + 255) / 256) * 256;
        return p;
    };
    float* w0T = alloc(147 * 9 * 16);
    float* w1T = alloc(144 * 9 * 32);
    float* w2T = alloc(288 * 9 * 64);
    float* wcT = alloc(64 * 9 * 200);
    float* h0  = alloc(8 * 16 * 112 * 112);
    float* p0  = alloc(8 * 16 * 56 * 56);
    float* h1  = alloc(8 * 32 * 28 * 28);
    float* p1  = alloc(8 * 32 * 14 * 14);
    float* h2  = alloc(8 * 64 * 7 * 7);
    float* mn  = alloc(8 * 64);

    // Weight packing (scaled spline weights, transposed layout)
    pack_w9T<<<(16 * 147 + 255) / 256, 256, 0, stream>>>(bw0, sw0, sc0, w0T, 16, 147);
    pack_w9T<<<(32 * 144 + 255) / 256, 256, 0, stream>>>(bw1, sw1, sc1, w1T, 32, 144);
    pack_w9T<<<(64 * 288 + 255) / 256, 256, 0, stream>>>(bw2, sw2, sc2, w2T, 64, 288);
    pack_w9T<<<(200 * 64 + 255) / 256, 256, 0, stream>>>(bwc, swc, scc, wcT, 200, 64);

    // Layer 0: (8,3,224,224) -> (8,16,112,112) -> pool (8,16,56,56)
    kan_conv<3, 7, 16, 2, 3, 8, 2><<<(8 * 112 * 112) / 8, 256, 0, stream>>>(
        x, w0T, h0, 8, 224, 224, 112, 112);
    maxpool2x2<<<(8 * 16 * 56 * 56 + 255) / 256, 256, 0, stream>>>(
        h0, p0, 112, 112, 8 * 16 * 56 * 56);

    // Layer 1: (8,16,56,56) -> (8,32,28,28) -> pool (8,32,14,14)
    kan_conv<16, 3, 32, 2, 1, 8, 1><<<(8 * 28 * 28) / 8, 256, 0, stream>>>(
        p0, w1T, h1, 8, 56, 56, 28, 28);
    maxpool2x2<<<(8 * 32 * 14 * 14 + 255) / 256, 256, 0, stream>>>(
        h1, p1, 28, 28, 8 * 32 * 14 * 14);

    // Layer 2: (8,32,14,14) -> (8,64,7,7)
    kan_conv<32, 3, 64, 2, 1, 4, 1><<<(8 * 7 * 7) / 4, 256, 0, stream>>>(
        p1, w2T, h2, 8, 14, 14, 7, 7);

    // Global average pool + classifier
    mean_hw<<<2, 256, 0, stream>>>(h2, mn, 49, 8 * 64);
    kan_head<<<8, 256, 0, stream>>>(mn, wcT, out);
}

// Round 2
// 284.887 us; speedup vs baseline: 4.5424x; 4.5424x over previous
//
#include <hip/hip_runtime.h>

#define DEV __device__ __forceinline__

typedef _Float16 f16x8 __attribute__((ext_vector_type(8)));
typedef float f32x4 __attribute__((ext_vector_type(4)));

// Knot j of the extended uniform grid: (j-3)*h + (-1), h = 0.4f  (fp32, matches jnp)
DEV float knot(int j) { return (float)(j - 3) * 0.4f - 1.0f; }

// f[0] = silu(x), f[1..8] = cubic B-spline bases (Cox-de Boor, grid_size=5, order=3)
DEV void kan_feats(float x, float* f) {
    float b[11];
#pragma unroll
    for (int j = 0; j < 11; ++j)
        b[j] = (x >= knot(j) && x < knot(j + 1)) ? 1.0f : 0.0f;
#pragma unroll
    for (int k = 1; k <= 3; ++k) {
#pragma unroll
        for (int j = 0; j < 11 - k; ++j) {
            const float left  = (x - knot(j)) * (1.0f / (knot(j + k) - knot(j)));
            const float right = (knot(j + k + 1) - x) * (1.0f / (knot(j + k + 1) - knot(j + 1)));
            b[j] = left * b[j] + right * b[j + 1];
        }
    }
    f[0] = x / (1.0f + __expf(-x));
#pragma unroll
    for (int t = 0; t < 8; ++t) f[t + 1] = b[t];
}

DEV unsigned short f16b(float x) {
    _Float16 h = (_Float16)x;  // v_cvt_f16_f32, RNE
    return __builtin_bit_cast(unsigned short, h);
}

// Pack weights into B-fragment octet layout, f16:
//   W2[(k>>3)*OUT_F*8 + o*8 + (k&7)] = w(k,o),  k = i*9 + t  (t=0 base, t=1+s spline*scaler)
// Pad region (k >= IN_F*9) is pre-zeroed via hipMemsetAsync.
template <int OUT_F, int IN_F>
__global__ __launch_bounds__(256) void pack_w2(
    const float* __restrict__ bw, const float* __restrict__ sw,
    const float* __restrict__ sc, _Float16* __restrict__ W2) {
    const int idx = blockIdx.x * blockDim.x + threadIdx.x;
    if (idx >= OUT_F * IN_F) return;
    const int o = idx / IN_F, i = idx - o * IN_F;
    const float s = sc[idx];
    {
        const int k = i * 9;
        W2[((k >> 3) * OUT_F + o) * 8 + (k & 7)] = (_Float16)bw[idx];
    }
#pragma unroll
    for (int t = 0; t < 8; ++t) {
        const int k = i * 9 + 1 + t;
        W2[((k >> 3) * OUT_F + o) * 8 + (k & 7)] = (_Float16)(sw[idx * 8 + t] * s);
    }
}

// fp32 packed weights for the tiny classifier head: wT[(i*9+t)*out_f + o]
__global__ __launch_bounds__(256) void pack_w9T(
    const float* __restrict__ bw, const float* __restrict__ sw,
    const float* __restrict__ sc, float* __restrict__ dstT,
    int out_f, int in_f) {
    const int idx = blockIdx.x * blockDim.x + threadIdx.x;
    if (idx >= out_f * in_f) return;
    const int o = idx / in_f, i = idx - o * in_f;
    const float s = sc[idx];
    dstT[(i * 9 + 0) * out_f + o] = bw[idx];
#pragma unroll
    for (int k = 0; k < 8; ++k)
        dstT[(i * 9 + 1 + k) * out_f + o] = sw[idx * 8 + k] * s;
}

// Fused unfold + KAN-feature + f16 MFMA GEMM + relu.
// Block = 256 threads = 4 waves = MT row-tiles x OT o-tiles of 16x16.
// K (= CIN*KS*KS*9) processed in chunks of 288 (= 32 i's x 9 feats = 9 mfma k-steps),
// padded to NCH*288 with zero weights.
template <int CIN, int KS, int OUT_F, int STRIDE, int PAD, int ROWS, int MT, int OT,
          int Bn, int Hh, int Ww, int Ho, int Wo, int NCH>
__global__ __launch_bounds__(256) void kan_conv_mfma(
    const float* __restrict__ in, const _Float16* __restrict__ W2,
    float* __restrict__ out) {
    constexpr int IN_F = CIN * KS * KS;
    constexpr int Ntot = Bn * Ho * Wo;
    constexpr int TPT = ROWS * 16 / 256;  // i-pair tasks per thread per chunk
    static_assert(MT * OT == 4, "4 waves");
    static_assert(ROWS == MT * 16, "rows per block");

    __shared__ __align__(16) _Float16 feat[ROWS * 296];  // pitch 296 halves = 592 B
    unsigned int* featW = (unsigned int*)feat;

    const int tid = threadIdx.x;
    const int wave = tid >> 6, lane = tid & 63;
    const int mt = wave % MT, ot = wave / MT;
    const int n0 = blockIdx.x * ROWS;
    const int q = lane >> 4;
    const int l15 = lane & 15;

    f32x4 acc = {0.f, 0.f, 0.f, 0.f};
    const f16x8* __restrict__ Wv = (const f16x8*)W2;

    for (int c = 0; c < NCH; ++c) {
        const int i0 = c * 32;
        // ---- phase 1: features for ROWS x 32 i's into LDS (f16 pairs) ----
        float xs[2 * TPT];
#pragma unroll
        for (int t = 0; t < TPT; ++t) {
            const int task = tid + t * 256;
            const int r = task >> 4, ip = task & 15;
            const int n = n0 + r;
            const int wo = n % Wo, ho = (n / Wo) % Ho, b = n / (Wo * Ho);
#pragma unroll
            for (int u = 0; u < 2; ++u) {
                const int i = i0 + 2 * ip + u;
                float x = 0.0f;
                if (n < Ntot && i < IN_F) {
                    const int ci = i / (KS * KS), rem = i - ci * (KS * KS);
                    const int kh = rem / KS, kw = rem - kh * KS;
                    const int hi = ho * STRIDE - PAD + kh, wi = wo * STRIDE - PAD + kw;
                    if (hi >= 0 && hi < Hh && wi >= 0 && wi < Ww)
                        x = in[((b * CIN + ci) * Hh + hi) * Ww + wi];
                }
                xs[2 * t + u] = x;
            }
        }
#pragma unroll
        for (int t = 0; t < TPT; ++t) {
            const int task = tid + t * 256;
            const int r = task >> 4, ip = task & 15;
            float f[18];
            kan_feats(xs[2 * t + 0], f);
            kan_feats(xs[2 * t + 1], f + 9);
            unsigned int* dst = featW + r * 148 + ip * 9;
#pragma unroll
            for (int p = 0; p < 9; ++p)
                dst[p] = (unsigned int)f16b(f[2 * p]) | ((unsigned int)f16b(f[2 * p + 1]) << 16);
        }
        __syncthreads();
        // ---- phase 2: 9 mfma k-steps on this chunk ----
        const char* arow = (const char*)feat + (mt * 16 + l15) * 592 + q * 16;
        const int ocol = ot * 16 + l15;
#pragma unroll
        for (int s = 0; s < 9; ++s) {
            f16x8 a = *(const f16x8*)(arow + s * 64);                 // A[m][k-octet]
            f16x8 bf = Wv[((c * 9 + s) * 4 + q) * OUT_F + ocol];      // B[k-octet][n]
            acc = __builtin_amdgcn_mfma_f32_16x16x32_f16(a, bf, acc, 0, 0, 0);
        }
        __syncthreads();
    }
    // ---- epilogue: C[row][o] with row=(q*4+reg), col=lane&15 (m89-verified layout) ----
    const int ocol = ot * 16 + l15;
#pragma unroll
    for (int reg = 0; reg < 4; ++reg) {
        const int n = n0 + mt * 16 + q * 4 + reg;
        if (n < Ntot) {
            const int wo = n % Wo, ho = (n / Wo) % Ho, b = n / (Wo * Ho);
            out[((b * OUT_F + ocol) * Ho + ho) * Wo + wo] = fmaxf(acc[reg], 0.0f);
        }
    }
}

// 2x2/2 max pool over (B*C, Hi, Wi) -> (B*C, Hi/2, Wi/2); input already relu'd
__global__ __launch_bounds__(256) void maxpool2x2(
    const float* __restrict__ in, float* __restrict__ out,
    int Hi, int Wi, int total) {
    const int idx = blockIdx.x * blockDim.x + threadIdx.x;
    if (idx >= total) return;
    const int Wo = Wi >> 1, Ho = Hi >> 1;
    const int wo = idx % Wo, ho = (idx / Wo) % Ho, bc = idx / (Wo * Ho);
    const float* p = in + ((size_t)bc * Hi + ho * 2) * Wi + wo * 2;
    out[idx] = fmaxf(fmaxf(p[0], p[1]), fmaxf(p[Wi], p[Wi + 1]));
}

__global__ __launch_bounds__(256) void mean_hw(
    const float* __restrict__ in, float* __restrict__ out, int HW, int total) {
    const int idx = blockIdx.x * blockDim.x + threadIdx.x;
    if (idx >= total) return;
    const float* p = in + (size_t)idx * HW;
    float s = 0.0f;
    for (int j = 0; j < HW; ++j) s += p[j];
    out[idx] = s / (float)HW;
}

// Classifier KAN-linear: in (8,64) -> out (8,200), fp32, no relu
__global__ __launch_bounds__(256) void kan_head(
    const float* __restrict__ in, const float* __restrict__ wT,
    float* __restrict__ out) {
    __shared__ float feat[64 * 9];
    const int n = blockIdx.x;
    const int tid = threadIdx.x;
    if (tid < 64) {
        float f9[9];
        kan_feats(in[n * 64 + tid], f9);
#pragma unroll
        for (int t = 0; t < 9; ++t) feat[tid * 9 + t] = f9[t];
    }
    __syncthreads();
    if (tid < 200) {
        float sum = 0.0f;
        for (int j = 0; j < 576; ++j)
            sum += feat[j] * wT[j * 200 + tid];
        out[n * 200 + tid] = sum;
    }
}

extern "C" void kernel_launch(void* const* d_in, const int* in_sizes, int n_in,
                              void* d_out, int out_size, void* d_ws, size_t ws_size,
                              hipStream_t stream) {
    const float* x   = (const float*)d_in[0];
    const float* bw0 = (const float*)d_in[1];
    const float* sw0 = (const float*)d_in[2];
    const float* sc0 = (const float*)d_in[3];
    const float* bw1 = (const float*)d_in[4];
    const float* sw1 = (const float*)d_in[5];
    const float* sc1 = (const float*)d_in[6];
    const float* bw2 = (const float*)d_in[7];
    const float* sw2 = (const float*)d_in[8];
    const float* sc2 = (const float*)d_in[9];
    const float* bwc = (const float*)d_in[10];
    const float* swc = (const float*)d_in[11];
    const float* scc = (const float*)d_in[12];
    float* out = (float*)d_out;

    char* ws = (char*)d_ws;
    size_t off = 0;
    auto alloc = [&](size_t nbytes) {
        char* p = ws + off;
        off += (nbytes + 255) & ~(size_t)255;
        return p;
    };
    _Float16* W2_0 = (_Float16*)alloc(5 * 288 * 16 * 2);   // K padded to 1440
    _Float16* W2_1 = (_Float16*)alloc(5 * 288 * 32 * 2);   // K padded to 1440
    _Float16* W2_2 = (_Float16*)alloc(9 * 288 * 64 * 2);   // K = 2592 exact
    float* wcT = (float*)alloc(576 * 200 * 4);
    float* h0  = (float*)alloc((size_t)8 * 16 * 112 * 112 * 4);
    float* p0  = (float*)alloc((size_t)8 * 16 * 56 * 56 * 4);
    float* h1  = (float*)alloc((size_t)8 * 32 * 28 * 28 * 4);
    float* p1  = (float*)alloc((size_t)8 * 32 * 14 * 14 * 4);
    float* h2  = (float*)alloc((size_t)8 * 64 * 7 * 7 * 4);
    float* mn  = (float*)alloc(8 * 64 * 4);

    // Zero weight pads (k >= K_real contributes 0 even though B-spline(0) != 0)
    hipMemsetAsync(W2_0, 0, 5 * 288 * 16 * 2, stream);
    hipMemsetAsync(W2_1, 0, 5 * 288 * 32 * 2, stream);
    hipMemsetAsync(W2_2, 0, 9 * 288 * 64 * 2, stream);

    pack_w2<16, 147><<<(16 * 147 + 255) / 256, 256, 0, stream>>>(bw0, sw0, sc0, W2_0);
    pack_w2<32, 144><<<(32 * 144 + 255) / 256, 256, 0, stream>>>(bw1, sw1, sc1, W2_1);
    pack_w2<64, 288><<<(64 * 288 + 255) / 256, 256, 0, stream>>>(bw2, sw2, sc2, W2_2);
    pack_w9T<<<(200 * 64 + 255) / 256, 256, 0, stream>>>(bwc, swc, scc, wcT, 200, 64);

    // L0: (8,3,224,224) -> (8,16,112,112); N=100352 rows, K=1323->1440
    kan_conv_mfma<3, 7, 16, 2, 3, 64, 4, 1, 8, 224, 224, 112, 112, 5>
        <<<100352 / 64, 256, 0, stream>>>(x, W2_0, h0);
    maxpool2x2<<<(8 * 16 * 56 * 56 + 255) / 256, 256, 0, stream>>>(
        h0, p0, 112, 112, 8 * 16 * 56 * 56);

    // L1: (8,16,56,56) -> (8,32,28,28); N=6272 rows, K=1296->1440
    kan_conv_mfma<16, 3, 32, 2, 1, 32, 2, 2, 8, 56, 56, 28, 28, 5>
        <<<6272 / 32, 256, 0, stream>>>(p0, W2_1, h1);
    maxpool2x2<<<(8 * 32 * 14 * 14 + 255) / 256, 256, 0, stream>>>(
        h1, p1, 28, 28, 8 * 32 * 14 * 14);

    // L2: (8,32,14,14) -> (8,64,7,7); N=392 rows, K=2592
    kan_conv_mfma<32, 3, 64, 2, 1, 16, 1, 4, 8, 14, 14, 7, 7, 9>
        <<<(392 + 15) / 16, 256, 0, stream>>>(p1, W2_2, h2);

    // Global average pool + classifier head (fp32)
    mean_hw<<<2, 256, 0, stream>>>(h2, mn, 49, 8 * 64);
    kan_head<<<8, 256, 0, stream>>>(mn, wcT, out);
}

// Round 3
// 231.731 us; speedup vs baseline: 5.5844x; 1.2294x over previous
//
#include <hip/hip_runtime.h>

#define DEV __device__ __forceinline__

typedef _Float16 f16x8 __attribute__((ext_vector_type(8)));
typedef float f32x4 __attribute__((ext_vector_type(4)));
typedef unsigned int u32x4a __attribute__((ext_vector_type(4), aligned(4)));

// Knot j of the extended uniform grid: (j-3)*h + (-1), h = 0.4f (fp32, matches jnp)
DEV float knot(int j) { return (float)(j - 3) * 0.4f - 1.0f; }

// f[0] = silu(x), f[1..8] = cubic B-spline bases (Cox-de Boor, grid_size=5, order=3)
DEV void kan_feats(float x, float* f) {
    float b[11];
#pragma unroll
    for (int j = 0; j < 11; ++j)
        b[j] = (x >= knot(j) && x < knot(j + 1)) ? 1.0f : 0.0f;
#pragma unroll
    for (int k = 1; k <= 3; ++k) {
#pragma unroll
        for (int j = 0; j < 11 - k; ++j) {
            const float left  = (x - knot(j)) * (1.0f / (knot(j + k) - knot(j)));
            const float right = (knot(j + k + 1) - x) * (1.0f / (knot(j + k + 1) - knot(j + 1)));
            b[j] = left * b[j] + right * b[j + 1];
        }
    }
    f[0] = x / (1.0f + __expf(-x));
#pragma unroll
    for (int t = 0; t < 8; ++t) f[t + 1] = b[t];
}

DEV unsigned short f16b(float x) {
    _Float16 h = (_Float16)x;  // v_cvt_f16_f32, RNE
    return __builtin_bit_cast(unsigned short, h);
}

// Pack 9 features into 5 u32 (f16 pairs; 10th half = 0, its weight is also 0)
DEV void pack5(const float* f, unsigned int* w) {
    w[0] = (unsigned int)f16b(f[0]) | ((unsigned int)f16b(f[1]) << 16);
    w[1] = (unsigned int)f16b(f[2]) | ((unsigned int)f16b(f[3]) << 16);
    w[2] = (unsigned int)f16b(f[4]) | ((unsigned int)f16b(f[5]) << 16);
    w[3] = (unsigned int)f16b(f[6]) | ((unsigned int)f16b(f[7]) << 16);
    w[4] = (unsigned int)f16b(f[8]);
}

// Per-pixel featurization: in fp32 -> 20B packed f16 feature record
__global__ __launch_bounds__(256) void featurize(
    const float* __restrict__ in, unsigned int* __restrict__ fm, int total) {
    const int idx = blockIdx.x * 256 + threadIdx.x;
    if (idx >= total) return;
    float f[9];
    kan_feats(in[idx], f);
    unsigned int w[5];
    pack5(f, w);
    unsigned int* d = fm + (size_t)idx * 5;
    d[0] = w[0]; d[1] = w[1]; d[2] = w[2]; d[3] = w[3]; d[4] = w[4];
}

// Fused 2x2/2 maxpool + featurize (input already relu'd)
__global__ __launch_bounds__(256) void poolfeat(
    const float* __restrict__ in, unsigned int* __restrict__ fm,
    int Hi, int Wi, int total) {
    const int idx = blockIdx.x * 256 + threadIdx.x;
    if (idx >= total) return;
    const int Wo = Wi >> 1, Ho = Hi >> 1;
    const int wo = idx % Wo, ho = (idx / Wo) % Ho, bc = idx / (Wo * Ho);
    const float* p = in + ((size_t)bc * Hi + 2 * ho) * Wi + 2 * wo;
    const float v = fmaxf(fmaxf(p[0], p[1]), fmaxf(p[Wi], p[Wi + 1]));
    float f[9];
    kan_feats(v, f);
    unsigned int w[5];
    pack5(f, w);
    unsigned int* d = fm + (size_t)idx * 5;
    d[0] = w[0]; d[1] = w[1]; d[2] = w[2]; d[3] = w[3]; d[4] = w[4];
}

// Weight packing: k = i*10 + t (t=0 base, t=1..8 spline*scaler, t=9 zero pad)
// B-fragment octet layout: W2[((k>>3)*OUT_F + o)*8 + (k&7)]
template <int OUT_F, int IN_F, int NI>
DEV void packW2sec(int idx, const float* bw, const float* sw, const float* sc,
                   _Float16* W2) {
    const int o = idx / NI, i = idx - o * NI;
    float vals[10];
    if (i < IN_F) {
        const int wi = o * IN_F + i;
        const float s = sc[wi];
        vals[0] = bw[wi];
#pragma unroll
        for (int t = 0; t < 8; ++t) vals[1 + t] = sw[wi * 8 + t] * s;
        vals[9] = 0.0f;
    } else {
#pragma unroll
        for (int t = 0; t < 10; ++t) vals[t] = 0.0f;
    }
#pragma unroll
    for (int t = 0; t < 10; ++t) {
        const int k = i * 10 + t;
        W2[((k >> 3) * OUT_F + o) * 8 + (k & 7)] = (_Float16)vals[t];
    }
}

// One kernel packs all three conv layers (f16) + classifier head (fp32, pitch 9)
__global__ __launch_bounds__(256) void pack_all(
    const float* __restrict__ bw0, const float* __restrict__ sw0, const float* __restrict__ sc0,
    const float* __restrict__ bw1, const float* __restrict__ sw1, const float* __restrict__ sc1,
    const float* __restrict__ bw2, const float* __restrict__ sw2, const float* __restrict__ sc2,
    const float* __restrict__ bwc, const float* __restrict__ swc, const float* __restrict__ scc,
    _Float16* __restrict__ W2_0, _Float16* __restrict__ W2_1, _Float16* __restrict__ W2_2,
    float* __restrict__ wcT) {
    const int idx = blockIdx.x * 256 + threadIdx.x;
    if (idx < 2560) {
        packW2sec<16, 147, 160>(idx, bw0, sw0, sc0, W2_0);
    } else if (idx < 2560 + 5120) {
        packW2sec<32, 144, 160>(idx - 2560, bw1, sw1, sc1, W2_1);
    } else if (idx < 7680 + 18432) {
        packW2sec<64, 288, 288>(idx - 7680, bw2, sw2, sc2, W2_2);
    } else if (idx < 26112 + 12800) {
        const int e = idx - 26112;
        const int o = e / 64, i = e - o * 64;
        const float s = scc[e];
        wcT[(i * 9 + 0) * 200 + o] = bwc[e];
#pragma unroll
        for (int t = 0; t < 8; ++t)
            wcT[(i * 9 + 1 + t) * 200 + o] = swc[e * 8 + t] * s;
    }
}

// Fused gather + f16 MFMA GEMM + relu over pre-featurized pixels.
// Block = 256 threads = 4 waves = MT row-tiles x OT o-tiles of 16x16.
// K chunked as 32 inputs x 10 halves = 320 k = 10 mfma steps per chunk.
template <int CIN, int KS, int OUT_F, int STRIDE, int PAD, int ROWS, int MT, int OT,
          int Bn, int Hh, int Ww, int Ho, int Wo, int NCH>
__global__ __launch_bounds__(256) void kan_conv_mfma(
    const unsigned int* __restrict__ fm, const _Float16* __restrict__ W2,
    float* __restrict__ out) {
    constexpr int IN_F = CIN * KS * KS;
    constexpr int Ntot = Bn * Ho * Wo;
    constexpr int TPT = ROWS / 8;      // row-tasks per thread per chunk
    constexpr int PITCH = 164;         // words; 164%32=4 -> uniform bank spread
    static_assert(MT * OT == 4 && ROWS == MT * 16, "4 waves of 16 rows");
    __shared__ unsigned int featW[ROWS * PITCH];

    const int tid = threadIdx.x;
    const int wave = tid >> 6, lane = tid & 63;
    const int mt = wave % MT, ot = wave / MT;
    const int n0 = blockIdx.x * ROWS;
    const int q = lane >> 4, l15 = lane & 15;

    // features of x=0 (reference zero-pads patch values, feats(0) != 0)
    unsigned int F0p[5];
    {
        float f0[9];
        kan_feats(0.0f, f0);
        pack5(f0, F0p);
    }

    // per-row precompute (rows fixed across chunks)
    const int i_in = tid & 31;
    const int rbase = tid >> 5;
    int hi0[TPT], wi0[TPT], pixb[TPT];
    bool rv[TPT];
#pragma unroll
    for (int t = 0; t < TPT; ++t) {
        const int n = n0 + rbase + t * 8;
        const int wo_ = n % Wo, ho_ = (n / Wo) % Ho, b_ = n / (Wo * Ho);
        rv[t] = (n < Ntot);
        hi0[t] = ho_ * STRIDE - PAD;
        wi0[t] = wo_ * STRIDE - PAD;
        pixb[t] = b_ * CIN * Hh * Ww;
    }

    f32x4 acc = {0.f, 0.f, 0.f, 0.f};
    const f16x8* __restrict__ Wv = (const f16x8*)W2;

    for (int c = 0; c < NCH; ++c) {
        // ---- phase 1: gather packed features for ROWS x 32 inputs into LDS ----
        const int ii = c * 32 + i_in;
        const int ci = ii / (KS * KS), rem = ii - ci * (KS * KS);
        const int kh = rem / KS, kw = rem - kh * KS;
        const bool iv = (ii < IN_F);
#pragma unroll
        for (int t = 0; t < TPT; ++t) {
            const int hi = hi0[t] + kh, wi = wi0[t] + kw;
            const bool v = iv && rv[t] && hi >= 0 && hi < Hh && wi >= 0 && wi < Ww;
            unsigned int w0 = F0p[0], w1 = F0p[1], w2 = F0p[2], w3 = F0p[3], w4 = F0p[4];
            if (v) {
                const unsigned int* p = fm + (size_t)(pixb[t] + (ci * Hh + hi) * Ww + wi) * 5;
                const u32x4a v4 = *(const u32x4a*)p;
                w0 = v4.x; w1 = v4.y; w2 = v4.z; w3 = v4.w; w4 = p[4];
            }
            unsigned int* d = featW + (rbase + t * 8) * PITCH + i_in * 5;
            d[0] = w0; d[1] = w1; d[2] = w2; d[3] = w3; d[4] = w4;
        }
        __syncthreads();
        // ---- phase 2: 10 mfma k-steps on this 320-k chunk ----
        const char* arow = (const char*)featW + (mt * 16 + l15) * (PITCH * 4) + q * 16;
        const int ocol = ot * 16 + l15;
#pragma unroll
        for (int s = 0; s < 10; ++s) {
            f16x8 a = *(const f16x8*)(arow + s * 64);             // A[m][k-octet]
            f16x8 bf = Wv[((c * 10 + s) * 4 + q) * OUT_F + ocol]; // B[k-octet][n]
            acc = __builtin_amdgcn_mfma_f32_16x16x32_f16(a, bf, acc, 0, 0, 0);
        }
        __syncthreads();
    }
    // ---- epilogue: C row = q*4+reg, col = lane&15 (m89-verified layout) ----
    const int ocol = ot * 16 + l15;
#pragma unroll
    for (int reg = 0; reg < 4; ++reg) {
        const int n = n0 + mt * 16 + q * 4 + reg;
        if (n < Ntot) {
            const int wo_ = n % Wo, ho_ = (n / Wo) % Ho, b_ = n / (Wo * Ho);
            out[((b_ * OUT_F + ocol) * Ho + ho_) * Wo + wo_] = fmaxf(acc[reg], 0.0f);
        }
    }
}

// Fused global-avg-pool + classifier KAN-linear: h2 (8,64,7,7) -> out (8,200), fp32
__global__ __launch_bounds__(256) void kan_head(
    const float* __restrict__ h2, const float* __restrict__ wT,
    float* __restrict__ out) {
    __shared__ float feat[64 * 9];
    const int n = blockIdx.x;
    const int tid = threadIdx.x;
    if (tid < 64) {
        const float* p = h2 + (n * 64 + tid) * 49;
        float s = 0.0f;
        for (int j = 0; j < 49; ++j) s += p[j];
        float f9[9];
        kan_feats(s / 49.0f, f9);
#pragma unroll
        for (int t = 0; t < 9; ++t) feat[tid * 9 + t] = f9[t];
    }
    __syncthreads();
    if (tid < 200) {
        float sum = 0.0f;
        for (int j = 0; j < 576; ++j)
            sum += feat[j] * wT[j * 200 + tid];
        out[n * 200 + tid] = sum;
    }
}

extern "C" void kernel_launch(void* const* d_in, const int* in_sizes, int n_in,
                              void* d_out, int out_size, void* d_ws, size_t ws_size,
                              hipStream_t stream) {
    const float* x   = (const float*)d_in[0];
    const float* bw0 = (const float*)d_in[1];
    const float* sw0 = (const float*)d_in[2];
    const float* sc0 = (const float*)d_in[3];
    const float* bw1 = (const float*)d_in[4];
    const float* sw1 = (const float*)d_in[5];
    const float* sc1 = (const float*)d_in[6];
    const float* bw2 = (const float*)d_in[7];
    const float* sw2 = (const float*)d_in[8];
    const float* sc2 = (const float*)d_in[9];
    const float* bwc = (const float*)d_in[10];
    const float* swc = (const float*)d_in[11];
    const float* scc = (const float*)d_in[12];
    float* out = (float*)d_out;

    char* ws = (char*)d_ws;
    size_t off = 0;
    auto alloc = [&](size_t nbytes) {
        char* p = ws + off;
        off += (nbytes + 255) & ~(size_t)255;
        return p;
    };
    // Weights
    _Float16* W2_0 = (_Float16*)alloc(1600 * 16 * 2);   // K' = 5*320
    _Float16* W2_1 = (_Float16*)alloc(1600 * 32 * 2);   // K' = 5*320
    _Float16* W2_2 = (_Float16*)alloc(2880 * 64 * 2);   // K' = 9*320
    float* wcT = (float*)alloc(576 * 200 * 4);
    // regA: featX (24.1MB), later reused for featP0 (8.0MB)
    unsigned int* regA = (unsigned int*)alloc((size_t)8 * 3 * 224 * 224 * 20);
    // regB: h0 (6.4MB), later h1 @0 / featP1 @1MB / h2 @2MB
    char* regB = alloc((size_t)8 * 16 * 112 * 112 * 4);

    unsigned int* featX  = regA;
    unsigned int* featP0 = regA;
    float* h0 = (float*)regB;
    float* h1 = (float*)regB;
    unsigned int* featP1 = (unsigned int*)(regB + (1 << 20));
    float* h2 = (float*)(regB + (2 << 20));

    // Pack all weights (writes zero pads too — no memset needed)
    pack_all<<<(38912 + 255) / 256, 256, 0, stream>>>(
        bw0, sw0, sc0, bw1, sw1, sc1, bw2, sw2, sc2, bwc, swc, scc,
        W2_0, W2_1, W2_2, wcT);

    // Featurize input pixels once (12x patch overlap at L0)
    featurize<<<(1204224 + 255) / 256, 256, 0, stream>>>(x, featX, 1204224);

    // L0: (8,3,224,224) -> (8,16,112,112); N=100352, K=1470->1600
    kan_conv_mfma<3, 7, 16, 2, 3, 64, 4, 1, 8, 224, 224, 112, 112, 5>
        <<<100352 / 64, 256, 0, stream>>>(featX, W2_0, h0);
    poolfeat<<<(401408 + 255) / 256, 256, 0, stream>>>(h0, featP0, 112, 112, 401408);

    // L1: (8,16,56,56) -> (8,32,28,28); N=6272, K=1440->1600
    kan_conv_mfma<16, 3, 32, 2, 1, 32, 2, 2, 8, 56, 56, 28, 28, 5>
        <<<6272 / 32, 256, 0, stream>>>(featP0, W2_1, h1);
    poolfeat<<<(50176 + 255) / 256, 256, 0, stream>>>(h1, featP1, 28, 28, 50176);

    // L2: (8,32,14,14) -> (8,64,7,7); N=392, K=2880 exact
    kan_conv_mfma<32, 3, 64, 2, 1, 16, 1, 4, 8, 14, 14, 7, 7, 9>
        <<<(392 + 15) / 16, 256, 0, stream>>>(featP1, W2_2, h2);

    // Global average pool + classifier head (fp32)
    kan_head<<<8, 256, 0, stream>>>(h2, wcT, out);
}

// Round 6
// 204.461 us; speedup vs baseline: 6.3292x; 1.1334x over previous
//
#include <hip/hip_runtime.h>

#define DEV __device__ __forceinline__

typedef _Float16 f16x8 __attribute__((ext_vector_type(8)));
typedef float f32x4 __attribute__((ext_vector_type(4)));
typedef unsigned int u32x4a __attribute__((ext_vector_type(4), aligned(4)));

// Knot j of the extended uniform grid: (j-3)*h + (-1), h = 0.4f (fp32, matches jnp)
DEV float knot(int j) { return (float)(j - 3) * 0.4f - 1.0f; }

// f[0] = silu(x), f[1..8] = cubic B-spline bases (Cox-de Boor, grid_size=5, order=3)
DEV void kan_feats(float x, float* f) {
    float b[11];
#pragma unroll
    for (int j = 0; j < 11; ++j)
        b[j] = (x >= knot(j) && x < knot(j + 1)) ? 1.0f : 0.0f;
#pragma unroll
    for (int k = 1; k <= 3; ++k) {
#pragma unroll
        for (int j = 0; j < 11 - k; ++j) {
            const float left  = (x - knot(j)) * (1.0f / (knot(j + k) - knot(j)));
            const float right = (knot(j + k + 1) - x) * (1.0f / (knot(j + k + 1) - knot(j + 1)));
            b[j] = left * b[j] + right * b[j + 1];
        }
    }
    f[0] = x / (1.0f + __expf(-x));
#pragma unroll
    for (int t = 0; t < 8; ++t) f[t + 1] = b[t];
}

DEV unsigned short f16b(float x) {
    _Float16 h = (_Float16)x;  // v_cvt_f16_f32, RNE
    return __builtin_bit_cast(unsigned short, h);
}

// Pack 9 features into 5 u32 (f16 pairs; 10th half = 0, its weight is also 0)
DEV void pack5(const float* f, unsigned int* w) {
    w[0] = (unsigned int)f16b(f[0]) | ((unsigned int)f16b(f[1]) << 16);
    w[1] = (unsigned int)f16b(f[2]) | ((unsigned int)f16b(f[3]) << 16);
    w[2] = (unsigned int)f16b(f[4]) | ((unsigned int)f16b(f[5]) << 16);
    w[3] = (unsigned int)f16b(f[6]) | ((unsigned int)f16b(f[7]) << 16);
    w[4] = (unsigned int)f16b(f[8]);
}

// One thread packs one 16B weight octet (coalesced dwordx4 store).
// k = i*10 + t (t=0 base, t=1..8 spline*scaler, t=9 pad); W2[g*8 + (k&7)], g=(k>>3)*OUT_F+o
template <int OUT_F, int IN_F>
DEV void pack_oct(int g, const float* bw, const float* sw, const float* sc,
                  _Float16* W2) {
    const int o = g % OUT_F, k0 = (g / OUT_F) * 8;
    f16x8 v;
#pragma unroll
    for (int t = 0; t < 8; ++t) {
        const int k = k0 + t, i = k / 10, s = k - i * 10;
        float val = 0.0f;
        if (i < IN_F && s < 9) {
            const int wi = o * IN_F + i;
            val = (s == 0) ? bw[wi] : sw[wi * 8 + (s - 1)] * sc[wi];
        }
        v[t] = (_Float16)val;
    }
    *(f16x8*)(W2 + g * 8) = v;
}

#define FEAT_TOTAL 1204224  // 8*3*224*224
#define FEAT_BLOCKS 4704
#define G0 3200   // (1600/8)*16
#define G1 6400   // (1600/8)*32
#define G2 23040  // (2880/8)*64

// Fused: per-pixel featurization of x + all weight packing
__global__ __launch_bounds__(256) void prep(
    const float* __restrict__ x, unsigned int* __restrict__ fm,
    const float* __restrict__ bw0, const float* __restrict__ sw0, const float* __restrict__ sc0,
    const float* __restrict__ bw1, const float* __restrict__ sw1, const float* __restrict__ sc1,
    const float* __restrict__ bw2, const float* __restrict__ sw2, const float* __restrict__ sc2,
    const float* __restrict__ bwc, const float* __restrict__ swc, const float* __restrict__ scc,
    _Float16* __restrict__ W2_0, _Float16* __restrict__ W2_1, _Float16* __restrict__ W2_2,
    float* __restrict__ wcT) {
    const int bx = blockIdx.x;
    if (bx < FEAT_BLOCKS) {
        const int idx = bx * 256 + threadIdx.x;
        float f[9];
        kan_feats(x[idx], f);
        unsigned int w[5];
        pack5(f, w);
        unsigned int* d = fm + (size_t)idx * 5;
        d[0] = w[0]; d[1] = w[1]; d[2] = w[2]; d[3] = w[3]; d[4] = w[4];
        return;
    }
    const int e = (bx - FEAT_BLOCKS) * 256 + threadIdx.x;
    if (e < G0) {
        pack_oct<16, 147>(e, bw0, sw0, sc0, W2_0);
    } else if (e < G0 + G1) {
        pack_oct<32, 144>(e - G0, bw1, sw1, sc1, W2_1);
    } else if (e < G0 + G1 + G2) {
        pack_oct<64, 288>(e - G0 - G1, bw2, sw2, sc2, W2_2);
    } else if (e < G0 + G1 + G2 + 12800) {
        const int ee = e - G0 - G1 - G2;
        const int o = ee / 64, i = ee - o * 64;
        const float s = scc[ee];
        wcT[(i * 9 + 0) * 200 + o] = bwc[ee];
#pragma unroll
        for (int t = 0; t < 8; ++t)
            wcT[(i * 9 + 1 + t) * 200 + o] = swc[ee * 8 + t] * s;
    }
}

// Fused 2x2/2 maxpool + featurize (input already relu'd)
__global__ __launch_bounds__(256) void poolfeat(
    const float* __restrict__ in, unsigned int* __restrict__ fm,
    int Hi, int Wi, int total) {
    const int idx = blockIdx.x * 256 + threadIdx.x;
    if (idx >= total) return;
    const int Wo = Wi >> 1, Ho = Hi >> 1;
    const int wo = idx % Wo, ho = (idx / Wo) % Ho, bc = idx / (Wo * Ho);
    const float* p = in + ((size_t)bc * Hi + 2 * ho) * Wi + 2 * wo;
    const float v = fmaxf(fmaxf(p[0], p[1]), fmaxf(p[Wi], p[Wi + 1]));
    float f[9];
    kan_feats(v, f);
    unsigned int w[5];
    pack5(f, w);
    unsigned int* d = fm + (size_t)idx * 5;
    d[0] = w[0]; d[1] = w[1]; d[2] = w[2]; d[3] = w[3]; d[4] = w[4];
}

// Fused gather + f16 MFMA GEMM (+ relu or atomic accumulate).
// Rows = spatial TH x TW tile (exact) or linear with bounds (TH==0).
// blockIdx.y selects a CSEG-chunk K segment (for K-split layers).
template <int CIN, int KS, int OUT_F, int STRIDE, int PAD, int ROWS, int MT, int OT,
          int Bn, int Hh, int Ww, int Ho, int Wo, int TH, int TW, int CSEG, int NCH,
          bool ATOMIC>
__global__ __launch_bounds__(MT * OT * 64) void kan_conv_mfma(
    const unsigned int* __restrict__ fm, const _Float16* __restrict__ W2,
    float* __restrict__ out) {
    constexpr int THREADS = MT * OT * 64;
    constexpr int IN_F = CIN * KS * KS;
    constexpr int Ntot = Bn * Ho * Wo;
    constexpr int RPI = THREADS / 32;  // rows gathered per iteration
    constexpr int TPT = ROWS / RPI;    // gather tasks per thread
    constexpr int PITCH = 164;         // words; 164%32=4 -> lanes spread across banks
    static_assert(ROWS == MT * 16, "row tiles");
    __shared__ unsigned int featW[ROWS * PITCH];

    const int tid = threadIdx.x;
    const int wave = tid >> 6, lane = tid & 63;
    const int mt = wave % MT, ot = wave / MT;
    const int q = lane >> 4, l15 = lane & 15;
    const int cbeg = blockIdx.y * CSEG;
    const int cend = (cbeg + CSEG < NCH) ? cbeg + CSEG : NCH;

    // row -> (b, ho, wo)
    auto rowmap = [&](int r, int& b_, int& ho_, int& wo_) -> bool {
        if constexpr (TH > 0) {
            constexpr int NTW = Wo / TW, NTH = Ho / TH;
            const int bt = blockIdx.x;
            b_ = bt / (NTH * NTW);
            const int rem = bt - b_ * (NTH * NTW);
            ho_ = (rem / NTW) * TH + r / TW;
            wo_ = (rem - (rem / NTW) * NTW) * TW + (r - (r / TW) * TW);
            return true;
        } else {
            const int n = blockIdx.x * ROWS + r;
            wo_ = n % Wo; ho_ = (n / Wo) % Ho; b_ = n / (Wo * Ho);
            return n < Ntot;
        }
    };

    // features of x=0 (reference zero-pads patch values, feats(0) != 0)
    unsigned int F0p[5];
    {
        float f0[9];
        kan_feats(0.0f, f0);
        pack5(f0, F0p);
    }

    // per-row precompute (rows fixed across chunks)
    const int i_in = tid & 31;
    const int rbase = tid >> 5;
    int hi0[TPT], wi0[TPT], pixb[TPT];
    bool rv[TPT];
#pragma unroll
    for (int t = 0; t < TPT; ++t) {
        int b_, ho_, wo_;
        rv[t] = rowmap(rbase + t * RPI, b_, ho_, wo_);
        hi0[t] = ho_ * STRIDE - PAD;
        wi0[t] = wo_ * STRIDE - PAD;
        pixb[t] = b_ * CIN * Hh * Ww;
    }

    f32x4 acc = {0.f, 0.f, 0.f, 0.f};
    const f16x8* __restrict__ Wv = (const f16x8*)W2;

    for (int c = cbeg; c < cend; ++c) {
        // ---- phase 1: gather packed features for ROWS x 32 inputs into LDS ----
        const int ii = c * 32 + i_in;
        const int ci = ii / (KS * KS), rem = ii - ci * (KS * KS);
        const int kh = rem / KS, kw = rem - kh * KS;
        const bool iv = (ii < IN_F);
#pragma unroll
        for (int t = 0; t < TPT; ++t) {
            const int hi = hi0[t] + kh, wi = wi0[t] + kw;
            const bool v = iv && rv[t] && hi >= 0 && hi < Hh && wi >= 0 && wi < Ww;
            unsigned int w0 = F0p[0], w1 = F0p[1], w2 = F0p[2], w3 = F0p[3], w4 = F0p[4];
            if (v) {
                const unsigned int* p = fm + (size_t)(pixb[t] + (ci * Hh + hi) * Ww + wi) * 5;
                const u32x4a v4 = *(const u32x4a*)p;
                w0 = v4.x; w1 = v4.y; w2 = v4.z; w3 = v4.w; w4 = p[4];
            }
            unsigned int* d = featW + (rbase + t * RPI) * PITCH + i_in * 5;
            d[0] = w0; d[1] = w1; d[2] = w2; d[3] = w3; d[4] = w4;
        }
        __syncthreads();
        // ---- phase 2: 10 mfma k-steps on this 320-k chunk ----
        const char* arow = (const char*)featW + (mt * 16 + l15) * (PITCH * 4) + q * 16;
        const int ocol = ot * 16 + l15;
#pragma unroll
        for (int s = 0; s < 10; ++s) {
            f16x8 a = *(const f16x8*)(arow + s * 64);             // A[m][k-octet]
            f16x8 bf = Wv[((c * 10 + s) * 4 + q) * OUT_F + ocol]; // B[k-octet][n]
            acc = __builtin_amdgcn_mfma_f32_16x16x32_f16(a, bf, acc, 0, 0, 0);
        }
        __syncthreads();
    }
    // ---- epilogue: C row = q*4+reg, col = lane&15 (m89-verified layout) ----
    const int ocol = ot * 16 + l15;
#pragma unroll
    for (int reg = 0; reg < 4; ++reg) {
        int b_, ho_, wo_;
        const bool v = rowmap(mt * 16 + q * 4 + reg, b_, ho_, wo_);
        if (v) {
            float* dst = out + ((b_ * OUT_F + ocol) * Ho + ho_) * Wo + wo_;
            if constexpr (ATOMIC) atomicAdd(dst, acc[reg]);
            else *dst = fmaxf(acc[reg], 0.0f);
        }
    }
}

// Fused relu + global-avg-pool + classifier KAN-linear: h2 (8,64,7,7) raw sums -> out (8,200)
__global__ __launch_bounds__(256) void kan_head(
    const float* __restrict__ h2, const float* __restrict__ wT,
    float* __restrict__ out) {
    __shared__ float feat[64 * 9];
    const int n = blockIdx.x;
    const int tid = threadIdx.x;
    if (tid < 64) {
        const float* p = h2 + (n * 64 + tid) * 49;
        float s = 0.0f;
        for (int j = 0; j < 49; ++j) s += fmaxf(p[j], 0.0f);
        float f9[9];
        kan_feats(s / 49.0f, f9);
#pragma unroll
        for (int t = 0; t < 9; ++t) feat[tid * 9 + t] = f9[t];
    }
    __syncthreads();
    if (tid < 200) {
        float sum = 0.0f;
        for (int j = 0; j < 576; ++j)
            sum += feat[j] * wT[j * 200 + tid];
        out[n * 200 + tid] = sum;
    }
}

extern "C" void kernel_launch(void* const* d_in, const int* in_sizes, int n_in,
                              void* d_out, int out_size, void* d_ws, size_t ws_size,
                              hipStream_t stream) {
    const float* x   = (const float*)d_in[0];
    const float* bw0 = (const float*)d_in[1];
    const float* sw0 = (const float*)d_in[2];
    const float* sc0 = (const float*)d_in[3];
    const float* bw1 = (const float*)d_in[4];
    const float* sw1 = (const float*)d_in[5];
    const float* sc1 = (const float*)d_in[6];
    const float* bw2 = (const float*)d_in[7];
    const float* sw2 = (const float*)d_in[8];
    const float* sc2 = (const float*)d_in[9];
    const float* bwc = (const float*)d_in[10];
    const float* swc = (const float*)d_in[11];
    const float* scc = (const float*)d_in[12];
    float* out = (float*)d_out;

    char* ws = (char*)d_ws;
    size_t off = 0;
    auto alloc = [&](size_t nbytes) {
        char* p = ws + off;
        off += (nbytes + 255) & ~(size_t)255;
        return p;
    };
    _Float16* W2_0 = (_Float16*)alloc(1600 * 16 * 2);
    _Float16* W2_1 = (_Float16*)alloc(1600 * 32 * 2);
    _Float16* W2_2 = (_Float16*)alloc(2880 * 64 * 2);
    float* wcT = (float*)alloc(576 * 200 * 4);
    // DEDICATED h2: it is accumulated via atomics across L2's K-split blocks and
    // must NOT alias h0 (R4/R5 bug: h2 lived inside h0's region; L0 clobbered the
    // zeroed buffer after the memset -> atomicAdd onto stale activations).
    float* h2 = (float*)alloc(8 * 64 * 49 * 4);
    unsigned int* regA = (unsigned int*)alloc((size_t)FEAT_TOTAL * 20);  // featX / featP0
    char* regB = alloc((size_t)8 * 16 * 112 * 112 * 4);                  // h0 / h1+featP1

    unsigned int* featX  = regA;
    unsigned int* featP0 = regA;   // overwrites featX only after L0 consumed it
    float* h0 = (float*)regB;
    float* h1 = (float*)regB;      // h1 (0.77MB) < featP1 offset (1MB)
    unsigned int* featP1 = (unsigned int*)(regB + (1 << 20));

    // h2 accumulated atomically across K-split blocks -> zero it
    hipMemsetAsync(h2, 0, 8 * 64 * 49 * 4, stream);

    // Featurize input + pack all weights (one kernel)
    prep<<<FEAT_BLOCKS + 178, 256, 0, stream>>>(
        x, featX, bw0, sw0, sc0, bw1, sw1, sc1, bw2, sw2, sc2, bwc, swc, scc,
        W2_0, W2_1, W2_2, wcT);

    // L0: (8,3,224,224) -> (8,16,112,112); 4x8 spatial tiles, 128 thr
    kan_conv_mfma<3, 7, 16, 2, 3, 32, 2, 1, 8, 224, 224, 112, 112, 4, 8, 5, 5, false>
        <<<dim3(8 * 28 * 14, 1), 128, 0, stream>>>(featX, W2_0, h0);
    poolfeat<<<(401408 + 255) / 256, 256, 0, stream>>>(h0, featP0, 112, 112, 401408);

    // L1: (8,16,56,56) -> (8,32,28,28); 4x4 tiles, 128 thr, 392 blocks
    kan_conv_mfma<16, 3, 32, 2, 1, 16, 1, 2, 8, 56, 56, 28, 28, 4, 4, 5, 5, false>
        <<<dim3(8 * 7 * 7, 1), 128, 0, stream>>>(featP0, W2_1, h1);
    poolfeat<<<(50176 + 255) / 256, 256, 0, stream>>>(h1, featP1, 28, 28, 50176);

    // L2: (8,32,14,14) -> (8,64,7,7); linear rows, K-split x3 (atomic), 75 blocks
    kan_conv_mfma<32, 3, 64, 2, 1, 16, 1, 4, 8, 14, 14, 7, 7, 0, 0, 3, 9, true>
        <<<dim3(25, 3), 256, 0, stream>>>(featP1, W2_2, h2);

    // relu + global average pool + classifier head (fp32)
    kan_head<<<8, 256, 0, stream>>>(h2, wcT, out);
}

// Round 7
// 173.242 us; speedup vs baseline: 7.4697x; 1.1802x over previous
//
#include <hip/hip_runtime.h>

#define DEV __device__ __forceinline__

typedef _Float16 f16x8 __attribute__((ext_vector_type(8)));
typedef float f32x4 __attribute__((ext_vector_type(4)));
typedef unsigned int u32x4a __attribute__((ext_vector_type(4), aligned(4)));

// Knot j of the extended uniform grid: (j-3)*h + (-1), h = 0.4f (fp32, matches jnp)
DEV float knot(int j) { return (float)(j - 3) * 0.4f - 1.0f; }

// f[0] = silu(x), f[1..8] = cubic B-spline bases (Cox-de Boor, grid_size=5, order=3)
DEV void kan_feats(float x, float* f) {
    float b[11];
#pragma unroll
    for (int j = 0; j < 11; ++j)
        b[j] = (x >= knot(j) && x < knot(j + 1)) ? 1.0f : 0.0f;
#pragma unroll
    for (int k = 1; k <= 3; ++k) {
#pragma unroll
        for (int j = 0; j < 11 - k; ++j) {
            const float left  = (x - knot(j)) * (1.0f / (knot(j + k) - knot(j)));
            const float right = (knot(j + k + 1) - x) * (1.0f / (knot(j + k + 1) - knot(j + 1)));
            b[j] = left * b[j] + right * b[j + 1];
        }
    }
    f[0] = x / (1.0f + __expf(-x));
#pragma unroll
    for (int t = 0; t < 8; ++t) f[t + 1] = b[t];
}

DEV unsigned short f16b(float x) {
    _Float16 h = (_Float16)x;
    return __builtin_bit_cast(unsigned short, h);
}

DEV void pack5(const float* f, unsigned int* w) {
    w[0] = (unsigned int)f16b(f[0]) | ((unsigned int)f16b(f[1]) << 16);
    w[1] = (unsigned int)f16b(f[2]) | ((unsigned int)f16b(f[3]) << 16);
    w[2] = (unsigned int)f16b(f[4]) | ((unsigned int)f16b(f[5]) << 16);
    w[3] = (unsigned int)f16b(f[6]) | ((unsigned int)f16b(f[7]) << 16);
    w[4] = (unsigned int)f16b(f[8]);
}

// LDS A-plane offset (bytes) for input-index i; k-pitch 16, half-planes split.
// L0: i -> (ci, kh, kw) over 3x7x7; plane dims (parity, ci, ihp, iwh=19)
__device__ constexpr int d_l0(int ii) {
    const int i = ii > 146 ? 146 : ii;  // i=147 is zero-weight pad; any valid addr ok
    const int ci = i / 49, rem = i % 49, kh = rem / 7, kw = rem % 7;
    return ((((kw & 1) * 3 + ci) * 9 + kh) * 19 + (kw >> 1)) * 16;
}
// L1: i -> (ch, kh, kw) over 16x3x3; plane dims (parity, ch, ihp=9, iwh=5)
__device__ constexpr int d_l1(int i) {
    const int ch = i / 9, rem = i % 9, kh = rem / 3, kw = rem % 3;
    return ((((kw & 1) * 16 + ch) * 9 + kh) * 5 + (kw >> 1)) * 16;
}

// One thread packs one 16B weight octet. k = i*PITCH + t (t=0 base, t=1..8 spline*sc).
template <int OUT_F, int IN_F, int PITCH>
DEV void pack_oct(int g, const float* bw, const float* sw, const float* sc,
                  _Float16* W2) {
    const int o = g % OUT_F, k0 = (g / OUT_F) * 8;
    f16x8 v;
#pragma unroll
    for (int t = 0; t < 8; ++t) {
        const int k = k0 + t, i = k / PITCH, s = k - i * PITCH;
        float val = 0.0f;
        if (i < IN_F && s < 9) {
            const int wi = o * IN_F + i;
            val = (s == 0) ? bw[wi] : sw[wi * 8 + (s - 1)] * sc[wi];
        }
        v[t] = (_Float16)val;
    }
    *(f16x8*)(W2 + g * 8) = v;
}

#define PS0 4736   // L0: 296 koct * 16 o
#define PS1 9216   // L1: 288 koct * 32 o
#define PS2 23040  // L2: 360 koct * 64 o (pitch 10)
#define PS3 12800  // head: 200*64
#define PS4 25088  // h2 zero

// Pack all weights + zero h2 (h2 is atomically accumulated by L2)
__global__ __launch_bounds__(256) void prep(
    const float* __restrict__ bw0, const float* __restrict__ sw0, const float* __restrict__ sc0,
    const float* __restrict__ bw1, const float* __restrict__ sw1, const float* __restrict__ sc1,
    const float* __restrict__ bw2, const float* __restrict__ sw2, const float* __restrict__ sc2,
    const float* __restrict__ bwc, const float* __restrict__ swc, const float* __restrict__ scc,
    _Float16* __restrict__ W2_0, _Float16* __restrict__ W2_1, _Float16* __restrict__ W2_2,
    float* __restrict__ wcT, float* __restrict__ h2) {
    const int e = blockIdx.x * 256 + threadIdx.x;
    if (e < PS0) {
        pack_oct<16, 147, 16>(e, bw0, sw0, sc0, W2_0);
    } else if (e < PS0 + PS1) {
        pack_oct<32, 144, 16>(e - PS0, bw1, sw1, sc1, W2_1);
    } else if (e < PS0 + PS1 + PS2) {
        pack_oct<64, 288, 10>(e - PS0 - PS1, bw2, sw2, sc2, W2_2);
    } else if (e < PS0 + PS1 + PS2 + PS3) {
        const int ee = e - PS0 - PS1 - PS2;
        const int o = ee / 64, i = ee - o * 64;
        const float s = scc[ee];
        wcT[(i * 9 + 0) * 200 + o] = bwc[ee];
#pragma unroll
        for (int t = 0; t < 8; ++t)
            wcT[(i * 9 + 1 + t) * 200 + o] = swc[ee * 8 + t] * s;
    } else if (e < PS0 + PS1 + PS2 + PS3 + PS4) {
        h2[e - PS0 - PS1 - PS2 - PS3] = 0.0f;
    }
}

// L0: featurize-in-block + MFMA + fused relu/2x2-pool -> raw p0 (8,16,56,56)
// Tile: 2 ho x 16 wo outputs; 128 thr = 2 waves (wave = mt = ho row).
__global__ __launch_bounds__(128) void kan_conv0(
    const float* __restrict__ x, const _Float16* __restrict__ W2,
    float* __restrict__ p0) {
    constexpr int PLANE = 1026;  // 16B slots per half-plane: 2par*3ci*9ih*19iw
    __shared__ __align__(16) _Float16 feats[2 * PLANE * 8];  // 32.8 KB
    __shared__ float pbuf[2][8][16];
    const int tid = threadIdx.x;
    const int bx = blockIdx.x;
    const int b = bx / 392;          // 56*7 tiles per image
    const int r0 = bx - b * 392;
    const int bh = r0 / 7, bw = r0 - (r0 / 7) * 7;
    const int ih0 = bh * 4 - 3, iw0 = bw * 32 - 3;

    // featurize 1026 unique pixel slots (coalesced raw loads, feats(0) for OOB pad)
    for (int t = tid; t < 1026; t += 128) {
        const int iwh = t % 19;
        int r = t / 19;
        const int ihp = r % 9; r /= 9;
        const int ci = r % 3;
        const int p = r / 3;
        const int ih = ih0 + ihp, iw = iw0 + 2 * iwh + p;
        float xv = 0.0f;
        if (ih >= 0 && ih < 224 && iw >= 0 && iw < 224)
            xv = x[((b * 3 + ci) * 224 + ih) * 224 + iw];
        float f[9];
        kan_feats(xv, f);
        f16x8 lo, hi;
#pragma unroll
        for (int j = 0; j < 8; ++j) { lo[j] = (_Float16)f[j]; hi[j] = (_Float16)0.0f; }
        hi[0] = (_Float16)f[8];
        const int slot = ((p * 3 + ci) * 9 + ihp) * 19 + iwh;
        *(f16x8*)(feats + slot * 8) = lo;
        *(f16x8*)(feats + (PLANE + slot) * 8) = hi;
    }
    __syncthreads();

    const int lane = tid & 63, mt = tid >> 6;
    const int l15 = lane & 15, q = lane >> 4;
    const int qh = q & 1;
    const bool qi = (lane >> 5) & 1;
    // A addr = laneBase + const(i,half): vaddr16 = qh*PLANE + 38*mt + m + D(i)
    const char* aBase = (const char*)feats + (qh * PLANE + 38 * mt + l15) * 16;
    const f16x8* __restrict__ Wv = (const f16x8*)W2;
    f32x4 acc = {0.f, 0.f, 0.f, 0.f};
#pragma unroll
    for (int s = 0; s < 74; ++s) {
        const int aoff = qi ? d_l0(2 * s + 1) : d_l0(2 * s);
        const f16x8 a = *(const f16x8*)(aBase + aoff);
        const f16x8 bf = Wv[(s * 4 + q) * 16 + l15];
        acc = __builtin_amdgcn_mfma_f32_16x16x32_f16(a, bf, acc, 0, 0, 0);
    }
    // relu + horizontal pool pairs (C rows = wo): (q*4,q*4+1)->wp 2q, (q*4+2,+3)->2q+1
    pbuf[mt][2 * q + 0][l15] = fmaxf(fmaxf(acc[0], 0.f), fmaxf(acc[1], 0.f));
    pbuf[mt][2 * q + 1][l15] = fmaxf(fmaxf(acc[2], 0.f), fmaxf(acc[3], 0.f));
    __syncthreads();
    // vertical pool across the two ho rows (waves); write raw pooled value
    const int o = tid >> 3, wp = tid & 7;
    const float v = fmaxf(pbuf[0][wp][o], pbuf[1][wp][o]);
    p0[((b * 16 + o) * 56 + bh) * 56 + bw * 8 + wp] = v;
}

// L1: featurize-in-block from raw p0 + MFMA + fused relu/pool/featurize -> featP1 (AoS 20B)
// Tile: 4x4 outputs; 128 thr = 2 waves (wave = ot = o half).
__global__ __launch_bounds__(128) void kan_conv1(
    const float* __restrict__ p0, const _Float16* __restrict__ W2,
    unsigned int* __restrict__ featP1) {
    constexpr int PLANE = 1440;  // 2par*16ch*9ih*5iw
    __shared__ __align__(16) _Float16 feats[2 * PLANE * 8];  // 46 KB
    __shared__ float abuf[32][16];
    const int tid = threadIdx.x;
    const int bx = blockIdx.x;
    const int b = bx / 49;
    const int r0 = bx - b * 49;
    const int bh = r0 / 7, bw = r0 - (r0 / 7) * 7;
    const int ih0 = bh * 8 - 1, iw0 = bw * 8 - 1;

    for (int t = tid; t < 1296; t += 128) {
        const int iwp = t % 9;
        int r = t / 9;
        const int ihp = r % 9;
        const int ch = r / 9;
        const int ih = ih0 + ihp, iw = iw0 + iwp;
        float xv = 0.0f;
        if (ih >= 0 && ih < 56 && iw >= 0 && iw < 56)
            xv = p0[((b * 16 + ch) * 56 + ih) * 56 + iw];
        float f[9];
        kan_feats(xv, f);
        f16x8 lo, hi;
#pragma unroll
        for (int j = 0; j < 8; ++j) { lo[j] = (_Float16)f[j]; hi[j] = (_Float16)0.0f; }
        hi[0] = (_Float16)f[8];
        const int slot = (((iwp & 1) * 16 + ch) * 9 + ihp) * 5 + (iwp >> 1);
        *(f16x8*)(feats + slot * 8) = lo;
        *(f16x8*)(feats + (PLANE + slot) * 8) = hi;
    }
    __syncthreads();

    const int lane = tid & 63, ot = tid >> 6;
    const int l15 = lane & 15, q = lane >> 4;
    const int qh = q & 1;
    const bool qi = (lane >> 5) & 1;
    const int mh = l15 >> 2, mw = l15 & 3;
    const char* aBase = (const char*)feats + (qh * PLANE + mh * 10 + mw) * 16;
    const int ocol = ot * 16 + l15;
    const f16x8* __restrict__ Wv = (const f16x8*)W2;
    f32x4 acc = {0.f, 0.f, 0.f, 0.f};
#pragma unroll
    for (int s = 0; s < 72; ++s) {
        const int aoff = qi ? d_l1(2 * s + 1) : d_l1(2 * s);
        const f16x8 a = *(const f16x8*)(aBase + aoff);
        const f16x8 bf = Wv[(s * 4 + q) * 32 + ocol];
        acc = __builtin_amdgcn_mfma_f32_16x16x32_f16(a, bf, acc, 0, 0, 0);
    }
#pragma unroll
    for (int reg = 0; reg < 4; ++reg)
        abuf[ocol][q * 4 + reg] = fmaxf(acc[reg], 0.f);
    __syncthreads();
    // pooled: 32 o x (2hp x 2wp) = 128 tasks; featurize pooled value -> featP1
    const int o = tid >> 2, pp = tid & 3;
    const int hp = pp >> 1, wp = pp & 1;
    const float v00 = abuf[o][(2 * hp + 0) * 4 + 2 * wp + 0];
    const float v01 = abuf[o][(2 * hp + 0) * 4 + 2 * wp + 1];
    const float v10 = abuf[o][(2 * hp + 1) * 4 + 2 * wp + 0];
    const float v11 = abuf[o][(2 * hp + 1) * 4 + 2 * wp + 1];
    const float v = fmaxf(fmaxf(v00, v01), fmaxf(v10, v11));
    float f[9];
    kan_feats(v, f);
    unsigned int w[5];
    pack5(f, w);
    unsigned int* d = featP1 +
        (size_t)(((b * 32 + o) * 14 + bh * 2 + hp) * 14 + bw * 2 + wp) * 5;
    d[0] = w[0]; d[1] = w[1]; d[2] = w[2]; d[3] = w[3]; d[4] = w[4];
}

// L2 (gather-style over featP1 AoS records, K-split x3 with atomic accumulate)
template <int CIN, int KS, int OUT_F, int STRIDE, int PAD, int ROWS, int MT, int OT,
          int Bn, int Hh, int Ww, int Ho, int Wo, int CSEG, int NCH>
__global__ __launch_bounds__(MT * OT * 64) void kan_conv_mfma(
    const unsigned int* __restrict__ fm, const _Float16* __restrict__ W2,
    float* __restrict__ out) {
    constexpr int THREADS = MT * OT * 64;
    constexpr int IN_F = CIN * KS * KS;
    constexpr int Ntot = Bn * Ho * Wo;
    constexpr int RPI = THREADS / 32;
    constexpr int TPT = ROWS / RPI;
    constexpr int PITCH = 164;
    __shared__ unsigned int featW[ROWS * PITCH];

    const int tid = threadIdx.x;
    const int wave = tid >> 6, lane = tid & 63;
    const int mt = wave % MT, ot = wave / MT;
    const int q = lane >> 4, l15 = lane & 15;
    const int cbeg = blockIdx.y * CSEG;
    const int cend = (cbeg + CSEG < NCH) ? cbeg + CSEG : NCH;

    unsigned int F0p[5];
    {
        float f0[9];
        kan_feats(0.0f, f0);
        pack5(f0, F0p);
    }

    const int i_in = tid & 31;
    const int rbase = tid >> 5;
    int hi0[TPT], wi0[TPT], pixb[TPT];
    bool rv[TPT];
#pragma unroll
    for (int t = 0; t < TPT; ++t) {
        const int n = blockIdx.x * ROWS + rbase + t * RPI;
        const int wo_ = n % Wo, ho_ = (n / Wo) % Ho, b_ = n / (Wo * Ho);
        rv[t] = (n < Ntot);
        hi0[t] = ho_ * STRIDE - PAD;
        wi0[t] = wo_ * STRIDE - PAD;
        pixb[t] = b_ * CIN * Hh * Ww;
    }

    f32x4 acc = {0.f, 0.f, 0.f, 0.f};
    const f16x8* __restrict__ Wv = (const f16x8*)W2;

    for (int c = cbeg; c < cend; ++c) {
        const int ii = c * 32 + i_in;
        const int ci = ii / (KS * KS), rem = ii - ci * (KS * KS);
        const int kh = rem / KS, kw = rem - kh * KS;
        const bool iv = (ii < IN_F);
#pragma unroll
        for (int t = 0; t < TPT; ++t) {
            const int hi = hi0[t] + kh, wi = wi0[t] + kw;
            const bool v = iv && rv[t] && hi >= 0 && hi < Hh && wi >= 0 && wi < Ww;
            unsigned int w0 = F0p[0], w1 = F0p[1], w2 = F0p[2], w3 = F0p[3], w4 = F0p[4];
            if (v) {
                const unsigned int* p = fm + (size_t)(pixb[t] + (ci * Hh + hi) * Ww + wi) * 5;
                const u32x4a v4 = *(const u32x4a*)p;
                w0 = v4.x; w1 = v4.y; w2 = v4.z; w3 = v4.w; w4 = p[4];
            }
            unsigned int* d = featW + (rbase + t * RPI) * PITCH + i_in * 5;
            d[0] = w0; d[1] = w1; d[2] = w2; d[3] = w3; d[4] = w4;
        }
        __syncthreads();
        const char* arow = (const char*)featW + (mt * 16 + l15) * (PITCH * 4) + q * 16;
        const int ocol = ot * 16 + l15;
#pragma unroll
        for (int s = 0; s < 10; ++s) {
            f16x8 a = *(const f16x8*)(arow + s * 64);
            f16x8 bf = Wv[((c * 10 + s) * 4 + q) * OUT_F + ocol];
            acc = __builtin_amdgcn_mfma_f32_16x16x32_f16(a, bf, acc, 0, 0, 0);
        }
        __syncthreads();
    }
    const int ocol = ot * 16 + l15;
#pragma unroll
    for (int reg = 0; reg < 4; ++reg) {
        const int n = blockIdx.x * ROWS + mt * 16 + q * 4 + reg;
        if (n < Ntot) {
            const int wo_ = n % Wo, ho_ = (n / Wo) % Ho, b_ = n / (Wo * Ho);
            atomicAdd(out + ((b_ * OUT_F + ocol) * Ho + ho_) * Wo + wo_, acc[reg]);
        }
    }
}

// Fused relu + global-avg-pool + classifier KAN-linear: h2 raw sums -> out (8,200)
__global__ __launch_bounds__(256) void kan_head(
    const float* __restrict__ h2, const float* __restrict__ wT,
    float* __restrict__ out) {
    __shared__ float feat[64 * 9];
    const int n = blockIdx.x;
    const int tid = threadIdx.x;
    if (tid < 64) {
        const float* p = h2 + (n * 64 + tid) * 49;
        float s = 0.0f;
        for (int j = 0; j < 49; ++j) s += fmaxf(p[j], 0.0f);
        float f9[9];
        kan_feats(s / 49.0f, f9);
#pragma unroll
        for (int t = 0; t < 9; ++t) feat[tid * 9 + t] = f9[t];
    }
    __syncthreads();
    if (tid < 200) {
        float sum = 0.0f;
        for (int j = 0; j < 576; ++j)
            sum += feat[j] * wT[j * 200 + tid];
        out[n * 200 + tid] = sum;
    }
}

extern "C" void kernel_launch(void* const* d_in, const int* in_sizes, int n_in,
                              void* d_out, int out_size, void* d_ws, size_t ws_size,
                              hipStream_t stream) {
    const float* x   = (const float*)d_in[0];
    const float* bw0 = (const float*)d_in[1];
    const float* sw0 = (const float*)d_in[2];
    const float* sc0 = (const float*)d_in[3];
    const float* bw1 = (const float*)d_in[4];
    const float* sw1 = (const float*)d_in[5];
    const float* sc1 = (const float*)d_in[6];
    const float* bw2 = (const float*)d_in[7];
    const float* sw2 = (const float*)d_in[8];
    const float* sc2 = (const float*)d_in[9];
    const float* bwc = (const float*)d_in[10];
    const float* swc = (const float*)d_in[11];
    const float* scc = (const float*)d_in[12];
    float* out = (float*)d_out;

    char* ws = (char*)d_ws;
    size_t off = 0;
    auto alloc = [&](size_t nbytes) {
        char* p = ws + off;
        off += (nbytes + 255) & ~(size_t)255;
        return p;
    };
    _Float16* W2_0 = (_Float16*)alloc(296 * 16 * 8 * 2);   // K'=2368, pitch 16
    _Float16* W2_1 = (_Float16*)alloc(288 * 32 * 8 * 2);   // K'=2304, pitch 16
    _Float16* W2_2 = (_Float16*)alloc(360 * 64 * 8 * 2);   // K'=2880, pitch 10
    float* wcT = (float*)alloc(576 * 200 * 4);
    float* h2  = (float*)alloc(8 * 64 * 49 * 4);           // dedicated (atomic target)
    float* p0  = (float*)alloc((size_t)8 * 16 * 56 * 56 * 4);
    unsigned int* featP1 = (unsigned int*)alloc((size_t)8 * 32 * 14 * 14 * 20);

    // Pack weights + zero h2
    prep<<<(PS0 + PS1 + PS2 + PS3 + PS4 + 255) / 256, 256, 0, stream>>>(
        bw0, sw0, sc0, bw1, sw1, sc1, bw2, sw2, sc2, bwc, swc, scc,
        W2_0, W2_1, W2_2, wcT, h2);

    // L0 + pool fused: x -> p0 (raw pooled); 3136 blocks x 128 thr
    kan_conv0<<<8 * 56 * 7, 128, 0, stream>>>(x, W2_0, p0);

    // L1 + pool + featurize fused: p0 -> featP1; 392 blocks x 128 thr
    kan_conv1<<<8 * 7 * 7, 128, 0, stream>>>(p0, W2_1, featP1);

    // L2: gather-style, K-split x3 (atomic into h2); 75 blocks x 256 thr
    kan_conv_mfma<32, 3, 64, 2, 1, 16, 1, 4, 8, 14, 14, 7, 7, 3, 9>
        <<<dim3(25, 3), 256, 0, stream>>>(featP1, W2_2, h2);

    // relu + global average pool + classifier head (fp32)
    kan_head<<<8, 256, 0, stream>>>(h2, wcT, out);
}